// Round 4
// baseline (427.474 us; speedup 1.0000x reference)
//
#include <hip/hip_runtime.h>

#define BB 2
#define SS 2048
#define DD 1024
#define HH 16
#define WW 64
#define MM (BB*SS)  // 4096

typedef float f32x4 __attribute__((ext_vector_type(4)));
typedef short s16x8 __attribute__((ext_vector_type(8)));

__device__ __forceinline__ unsigned short f2bf(float f) {
  return __builtin_bit_cast(unsigned short, (__bf16)f);
}
__device__ __forceinline__ float bf2f(unsigned short u) {
  return (float)__builtin_bit_cast(__bf16, u);
}

// ---------------- pre-pass: x fp32 -> bf16 ----------------
__global__ __launch_bounds__(256) void k_convert_x(const float* __restrict__ x,
                                                   unsigned short* __restrict__ xb) {
  int i = (blockIdx.x * 256 + threadIdx.x) * 4;
  float4 v = *(const float4*)(x + i);
  ushort4 o = make_ushort4(f2bf(v.x), f2bf(v.y), f2bf(v.z), f2bf(v.w));
  *(ushort4*)(xb + i) = o;
}

// ---------------- pre-pass: W (KxN fp32) -> Wt (NxK bf16) ----------------
__global__ __launch_bounds__(256) void k_transpose_w(const float* __restrict__ Wm,
                                                     unsigned short* __restrict__ Wt) {
  __shared__ float tile[32][33];
  int bn = blockIdx.x * 32;  // n (cols of W)
  int bk = blockIdx.y * 32;  // k (rows of W)
  int tx = threadIdx.x;      // 0..31
  int ty = threadIdx.y;      // 0..7
#pragma unroll
  for (int r = 0; r < 4; ++r)
    tile[ty + r * 8][tx] = Wm[(bk + ty + r * 8) * DD + bn + tx];
  __syncthreads();
#pragma unroll
  for (int r = 0; r < 4; ++r)
    Wt[(bn + ty + r * 8) * DD + bk + tx] = f2bf(tile[tx][ty + r * 8]);
}

// ---------------- bf16 MFMA GEMM: C = A(M,K) * Bt(N,K)^T + bias ----------------
// modes: 0 = write bf16 head-layout (B,H,S,W), scaled (Q)
//        1 = write bf16 per-head transposed (B,H,W,S)  (V^T)
//        2 = write bf16 head-layout (K)
//        3 = write fp32 row-major MxN (final output)
__global__ __launch_bounds__(256) void k_gemm(const unsigned short* __restrict__ A,
                                              const unsigned short* __restrict__ Bt,
                                              const float* __restrict__ bias,
                                              unsigned short* __restrict__ out_bf,
                                              float* __restrict__ out_f,
                                              int mode, float oscale) {
  constexpr int LDK = 40;  // padded K-stride (16B aligned rows, 2-way bank alias = free)
  __shared__ __align__(16) unsigned short As[64 * LDK];
  __shared__ __align__(16) unsigned short Bs[64 * LDK];
  const int m0 = blockIdx.y * 64, n0 = blockIdx.x * 64;
  const int t = threadIdx.x;
  const int wv = t >> 6, lane = t & 63;
  const int quad = lane >> 4, l16 = lane & 15;
  const int sr = t >> 2, sk = (t & 3) * 8;      // staging: row, k-offset (8 bf16 = 16B)
  const int wm = (wv >> 1) * 32, wn = (wv & 1) * 32;  // 2x2 wave arrangement
  f32x4 acc[2][2] = {};

  for (int k0 = 0; k0 < DD; k0 += 32) {
    uint4 av = *(const uint4*)(A + (m0 + sr) * DD + k0 + sk);
    uint4 bv = *(const uint4*)(Bt + (n0 + sr) * DD + k0 + sk);
    __syncthreads();
    *(uint4*)(As + sr * LDK + sk) = av;
    *(uint4*)(Bs + sr * LDK + sk) = bv;
    __syncthreads();
    s16x8 af[2], bfr[2];
#pragma unroll
    for (int i = 0; i < 2; ++i) {
      af[i]  = *(const s16x8*)(As + (wm + i * 16 + l16) * LDK + quad * 8);
      bfr[i] = *(const s16x8*)(Bs + (wn + i * 16 + l16) * LDK + quad * 8);
    }
#pragma unroll
    for (int mi = 0; mi < 2; ++mi)
#pragma unroll
      for (int ni = 0; ni < 2; ++ni)
        acc[mi][ni] = __builtin_amdgcn_mfma_f32_16x16x32_bf16(af[mi], bfr[ni], acc[mi][ni], 0, 0, 0);
  }

#pragma unroll
  for (int mi = 0; mi < 2; ++mi) {
#pragma unroll
    for (int ni = 0; ni < 2; ++ni) {
      int col = n0 + wn + ni * 16 + l16;
      float bb = bias[col];
#pragma unroll
      for (int r = 0; r < 4; ++r) {
        int row = m0 + wm + mi * 16 + quad * 4 + r;  // C/D: row = quad*4 + reg
        float v = (acc[mi][ni][r] + bb) * oscale;
        if (mode == 3) {
          out_f[row * DD + col] = v;
        } else {
          int b = row >> 11, s = row & (SS - 1);
          int h = col >> 6, w = col & 63;
          long off;
          if (mode == 1) off = (long)(b * HH + h) * (SS * WW) + (long)w * SS + s;
          else           off = (long)(b * HH + h) * (SS * WW) + (long)s * WW + w;
          out_bf[off] = f2bf(v);
        }
      }
    }
  }
}

// ---------------- MFMA flash attention, 16-query waves ----------------
// One wave (64 threads) per (b,h, 16-query tile) -> 4096 single-wave blocks
// (16 waves/CU available at <=128 VGPR). Keys in 64-wide tiles.
// Q,K in (B,H,S,W) bf16 (Q pre-scaled by log2(e)/8); Vt in (B,H,W,S).
// V fragments are loaded AFTER softmax so kf and vf are never live together
// (keeps peak VGPR ~105, no spill). exp2-domain softmax; masked scores give
// exp2(-inf)=0 so the P->LDS store is correct without extra zeroing.
__global__ __launch_bounds__(64, 4) void k_attn_mfma(const unsigned short* __restrict__ Q,
                                                     const unsigned short* __restrict__ K,
                                                     const unsigned short* __restrict__ Vt,
                                                     unsigned short* __restrict__ hm) {
  constexpr int LDP = 72;  // bf16 elems: b128 reads 16B-aligned, 2-way bank alias (free)
  __shared__ __align__(16) unsigned short Pl[16 * LDP];
  const int tq = (int)(gridDim.x - 1 - blockIdx.x);  // reversed: longest blocks first
  const int qb = tq * 16;
  const int bh = blockIdx.y;
  const int lane = threadIdx.x;
  const int quad = lane >> 4, l16 = lane & 15;
  const unsigned short* Qp = Q + (size_t)bh * SS * WW;
  const unsigned short* Kp = K + (size_t)bh * SS * WW;
  const unsigned short* Vp = Vt + (size_t)bh * WW * SS;

  // Q B-fragments (loop-invariant): B[n=q_local=l16][k=dim=quad*8+j]
  s16x8 qf[2];
#pragma unroll
  for (int c = 0; c < 2; ++c)
    qf[c] = *(const s16x8*)(Qp + (qb + l16) * WW + c * 32 + quad * 8);

  f32x4 O[4] = {};  // C/D: row=q=quad*4+r, col=dim=l16 (+16*ni)
  float m = -__builtin_inff(), l = 0.f;

  const int ktiles = qb / 64 + 1;
  for (int kt = 0; kt < ktiles; ++kt) {
    const int kb = kt * 64;

    // K A-fragments: A[m=key_local][k=dim]
    s16x8 kf[4][2];
#pragma unroll
    for (int mt = 0; mt < 4; ++mt)
#pragma unroll
      for (int c = 0; c < 2; ++c)
        kf[mt][c] = *(const s16x8*)(Kp + (kb + mt * 16 + l16) * WW + c * 32 + quad * 8);

    // S^T tiles: sc[mt], row=key_local=quad*4+r (+16*mt), col=q_local=l16
    f32x4 sc[4] = {};
#pragma unroll
    for (int mt = 0; mt < 4; ++mt)
#pragma unroll
      for (int c = 0; c < 2; ++c)
        sc[mt] = __builtin_amdgcn_mfma_f32_16x16x32_bf16(kf[mt][c], qf[c], sc[mt], 0, 0, 0);

    if (kt == ktiles - 1) {  // diagonal tile: causal mask
#pragma unroll
      for (int mt = 0; mt < 4; ++mt)
#pragma unroll
        for (int r = 0; r < 4; ++r)
          if (kb + mt * 16 + quad * 4 + r > qb + l16)
            sc[mt][r] = -__builtin_inff();
    }

    // online softmax (exp2 domain); stats per q = l16
    float mx = sc[0][0];
#pragma unroll
    for (int mt = 0; mt < 4; ++mt)
#pragma unroll
      for (int r = 0; r < 4; ++r) mx = fmaxf(mx, sc[mt][r]);
    mx = fmaxf(mx, __shfl_xor(mx, 16));
    mx = fmaxf(mx, __shfl_xor(mx, 32));
    float mn = fmaxf(m, mx);
    float alpha = exp2f(m - mn);
    float s = 0.f;
#pragma unroll
    for (int mt = 0; mt < 4; ++mt)
#pragma unroll
      for (int r = 0; r < 4; ++r) {
        float p = exp2f(sc[mt][r] - mn);
        sc[mt][r] = p;
        s += p;
      }
    s += __shfl_xor(s, 16);
    s += __shfl_xor(s, 32);
    l = l * alpha + s;
    m = mn;

    // rescale O: rows q = quad*4+r -> alpha lives at lane q (replicated /16)
#pragma unroll
    for (int r = 0; r < 4; ++r) {
      float aT = __shfl(alpha, quad * 4 + r);
#pragma unroll
      for (int ni = 0; ni < 4; ++ni) O[ni][r] *= aT;
    }

    // WAR: previous iteration's pf reads must be done before overwrite
    asm volatile("s_waitcnt lgkmcnt(0)" ::: "memory");
#pragma unroll
    for (int mt = 0; mt < 4; ++mt) {
      ushort4 pw = make_ushort4(f2bf(sc[mt][0]), f2bf(sc[mt][1]),
                                f2bf(sc[mt][2]), f2bf(sc[mt][3]));
      *(ushort4*)(Pl + l16 * LDP + mt * 16 + quad * 4) = pw;
    }
    // RAW: writes visible before fragment reads
    asm volatile("s_waitcnt lgkmcnt(0)" ::: "memory");

    // V^T B-fragments (loaded after kf is dead -> low peak VGPR):
    // B[n=dim_local=l16][k=key=quad*8+j]
    s16x8 vf[4][2];
#pragma unroll
    for (int ni = 0; ni < 4; ++ni)
#pragma unroll
      for (int c = 0; c < 2; ++c)
        vf[ni][c] = *(const s16x8*)(Vp + (ni * 16 + l16) * SS + kb + c * 32 + quad * 8);

    // P A-fragments: A[m=q_local=l16][k=key=quad*8+j]
    s16x8 pf[2];
#pragma unroll
    for (int c = 0; c < 2; ++c)
      pf[c] = *(const s16x8*)(Pl + l16 * LDP + c * 32 + quad * 8);

    // O += P * V^T
#pragma unroll
    for (int ni = 0; ni < 4; ++ni)
#pragma unroll
      for (int c = 0; c < 2; ++c)
        O[ni] = __builtin_amdgcn_mfma_f32_16x16x32_bf16(pf[c], vf[ni][c], O[ni], 0, 0, 0);
  }

  // epilogue: divide by l (broadcast per C/D row), write head-merged (B,S,D)
  const int b = bh >> 4, h = bh & 15;
#pragma unroll
  for (int r = 0; r < 4; ++r) {
    float linv = 1.f / __shfl(l, quad * 4 + r);
    int q = qb + quad * 4 + r;
#pragma unroll
    for (int ni = 0; ni < 4; ++ni)
      hm[(size_t)(b * SS + q) * DD + h * WW + ni * 16 + l16] = f2bf(O[ni][r] * linv);
  }
}

extern "C" void kernel_launch(void* const* d_in, const int* in_sizes, int n_in,
                              void* d_out, int out_size, void* d_ws, size_t ws_size,
                              hipStream_t stream) {
  const float* x  = (const float*)d_in[0];
  // d_in[1] = seg : unused by the reference
  const float* Wq = (const float*)d_in[2];
  const float* bq = (const float*)d_in[3];
  const float* Wk = (const float*)d_in[4];
  const float* bk = (const float*)d_in[5];
  const float* Wv = (const float*)d_in[6];
  const float* bv = (const float*)d_in[7];
  const float* Wo = (const float*)d_in[8];
  const float* bo = (const float*)d_in[9];
  float* out = (float*)d_out;

  char* ws = (char*)d_ws;
  unsigned short* xb  = (unsigned short*)(ws);                      // 8 MB  (4096x1024 bf16)
  unsigned short* Wtq = (unsigned short*)(ws + (size_t)( 8 << 20)); // 2 MB each
  unsigned short* Wtk = (unsigned short*)(ws + (size_t)(10 << 20));
  unsigned short* Wtv = (unsigned short*)(ws + (size_t)(12 << 20));
  unsigned short* Wto = (unsigned short*)(ws + (size_t)(14 << 20));
  unsigned short* Qb  = (unsigned short*)(ws + (size_t)(16 << 20)); // 8 MB (B,H,S,W)
  unsigned short* Kb  = (unsigned short*)(ws + (size_t)(24 << 20)); // 8 MB (B,H,S,W)
  unsigned short* Vtb = (unsigned short*)(ws + (size_t)(32 << 20)); // 8 MB (B,H,W,S)
  unsigned short* hm  = (unsigned short*)(ws + (size_t)(40 << 20)); // 8 MB (B,S,D) -> 48 MB total

  k_convert_x<<<dim3(MM * DD / 1024), 256, 0, stream>>>(x, xb);

  dim3 tg(32, 32), tb(32, 8);
  k_transpose_w<<<tg, tb, 0, stream>>>(Wq, Wtq);
  k_transpose_w<<<tg, tb, 0, stream>>>(Wk, Wtk);
  k_transpose_w<<<tg, tb, 0, stream>>>(Wv, Wtv);
  k_transpose_w<<<tg, tb, 0, stream>>>(Wo, Wto);

  dim3 gg(DD / 64, MM / 64);  // (16, 64)
  // Q pre-scaled by log2(e)/sqrt(64) so softmax runs in exp2 domain
  k_gemm<<<gg, 256, 0, stream>>>(xb, Wtq, bq, Qb, nullptr, 0, 0.125f * 1.4426950408889634f);
  k_gemm<<<gg, 256, 0, stream>>>(xb, Wtk, bk, Kb, nullptr, 2, 1.0f);    // K head-layout
  k_gemm<<<gg, 256, 0, stream>>>(xb, Wtv, bv, Vtb, nullptr, 1, 1.0f);   // V^T per head
  dim3 ag(SS / 16, BB * HH);  // (128, 32) = 4096 single-wave blocks
  k_attn_mfma<<<ag, 64, 0, stream>>>(Qb, Kb, Vtb, hm);

  k_gemm<<<gg, 256, 0, stream>>>(hm, Wto, bo, nullptr, out, 3, 1.0f);   // final projection, fp32
}

// Round 5
// 303.005 us; speedup vs baseline: 1.4108x; 1.4108x over previous
//
#include <hip/hip_runtime.h>

#define BB 2
#define SS 2048
#define DD 1024
#define HH 16
#define WW 64
#define MM (BB*SS)  // 4096

typedef float f32x4 __attribute__((ext_vector_type(4)));
typedef short s16x8 __attribute__((ext_vector_type(8)));

__device__ __forceinline__ unsigned short f2bf(float f) {
  return __builtin_bit_cast(unsigned short, (__bf16)f);
}
__device__ __forceinline__ float bf2f(unsigned short u) {
  return (float)__builtin_bit_cast(__bf16, u);
}
// async global->LDS DMA, 16B per lane; lptr must be wave-uniform
__device__ __forceinline__ void dma16(const unsigned short* g, unsigned short* l) {
  __builtin_amdgcn_global_load_lds(
      (const __attribute__((address_space(1))) unsigned int*)g,
      (__attribute__((address_space(3))) unsigned int*)l, 16, 0, 0);
}

// ---------------- pre-pass: x fp32 -> bf16 ----------------
__global__ __launch_bounds__(256) void k_convert_x(const float* __restrict__ x,
                                                   unsigned short* __restrict__ xb) {
  int i = (blockIdx.x * 256 + threadIdx.x) * 4;
  float4 v = *(const float4*)(x + i);
  ushort4 o = make_ushort4(f2bf(v.x), f2bf(v.y), f2bf(v.z), f2bf(v.w));
  *(ushort4*)(xb + i) = o;
}

// ---------------- pre-pass: W (KxN fp32) -> Wt (NxK bf16) ----------------
__global__ __launch_bounds__(256) void k_transpose_w(const float* __restrict__ Wm,
                                                     unsigned short* __restrict__ Wt) {
  __shared__ float tile[32][33];
  int bn = blockIdx.x * 32;
  int bk = blockIdx.y * 32;
  int tx = threadIdx.x;
  int ty = threadIdx.y;
#pragma unroll
  for (int r = 0; r < 4; ++r)
    tile[ty + r * 8][tx] = Wm[(bk + ty + r * 8) * DD + bn + tx];
  __syncthreads();
#pragma unroll
  for (int r = 0; r < 4; ++r)
    Wt[(bn + ty + r * 8) * DD + bk + tx] = f2bf(tile[tx][ty + r * 8]);
}

// ---------------- bf16 MFMA GEMM: C = A(M,K) * Bt(N,K)^T + bias ----------------
// 64x64 tile, BK=32, global_load_lds (width 16) staging with XOR-swizzled LDS:
// LDS slot (row, physblock16B) holds global (row, physblock ^ (row&3)).
// Fragment read of logical block lb of row r -> phys = lb ^ (r&3): 4-way bank
// spread (1.58x, acceptable) instead of 16-way from unpadded rows.
// modes: 0 = write bf16 head-layout (B,H,S,W), scaled (Q)
//        1 = write bf16 per-head transposed (B,H,W,S)  (V^T)
//        2 = write bf16 head-layout (K)
//        3 = write fp32 row-major MxN (final output)
__global__ __launch_bounds__(256) void k_gemm(const unsigned short* __restrict__ A,
                                              const unsigned short* __restrict__ Bt,
                                              const float* __restrict__ bias,
                                              unsigned short* __restrict__ out_bf,
                                              float* __restrict__ out_f,
                                              int mode, float oscale) {
  __shared__ __align__(16) unsigned short As[64 * 32];  // 4 KB
  __shared__ __align__(16) unsigned short Bs[64 * 32];  // 4 KB
  const int m0 = blockIdx.y * 64, n0 = blockIdx.x * 64;
  const int t = threadIdx.x;
  const int wv = t >> 6, lane = t & 63;
  const int quad = lane >> 4, l16 = lane & 15;
  const int wm = (wv >> 1) * 32, wn = (wv & 1) * 32;
  // DMA mapping: wave wv stages rows wv*16..wv*16+15 (1 KB chunk per wave)
  const int drow = wv * 16 + (lane >> 2);      // tile row this lane fetches
  const int dpb = lane & 3;                    // physical 16B block in row
  const int dcol = ((dpb ^ (drow & 3)) << 3);  // swizzled logical col (elems)
  const unsigned short* Arow = A + (size_t)(m0 + drow) * DD + dcol;
  const unsigned short* Brow = Bt + (size_t)(n0 + drow) * DD + dcol;
  unsigned short* AsDst = As + wv * 512;  // uniform chunk base
  unsigned short* BsDst = Bs + wv * 512;
  f32x4 acc[2][2] = {};

  for (int k0 = 0; k0 < DD; k0 += 32) {
    __syncthreads();  // previous iteration's ds_reads done before overwrite
    dma16(Arow + k0, AsDst);
    dma16(Brow + k0, BsDst);
    asm volatile("s_waitcnt vmcnt(0)" ::: "memory");  // this wave's DMA landed
    __syncthreads();                                  // all waves' DMA visible
    s16x8 af[2], bfr[2];
#pragma unroll
    for (int i = 0; i < 2; ++i) {
      int ra = wm + i * 16 + l16;
      int rb = wn + i * 16 + l16;
      af[i]  = *(const s16x8*)(As + ra * 32 + ((quad ^ (ra & 3)) << 3));
      bfr[i] = *(const s16x8*)(Bs + rb * 32 + ((quad ^ (rb & 3)) << 3));
    }
#pragma unroll
    for (int mi = 0; mi < 2; ++mi)
#pragma unroll
      for (int ni = 0; ni < 2; ++ni)
        acc[mi][ni] = __builtin_amdgcn_mfma_f32_16x16x32_bf16(af[mi], bfr[ni], acc[mi][ni], 0, 0, 0);
  }

#pragma unroll
  for (int mi = 0; mi < 2; ++mi) {
#pragma unroll
    for (int ni = 0; ni < 2; ++ni) {
      int col = n0 + wn + ni * 16 + l16;
      float bb = bias[col];
#pragma unroll
      for (int r = 0; r < 4; ++r) {
        int row = m0 + wm + mi * 16 + quad * 4 + r;  // C/D: row = quad*4 + reg
        float v = (acc[mi][ni][r] + bb) * oscale;
        if (mode == 3) {
          out_f[row * DD + col] = v;
        } else {
          int b = row >> 11, s = row & (SS - 1);
          int h = col >> 6, w = col & 63;
          long off;
          if (mode == 1) off = (long)(b * HH + h) * (SS * WW) + (long)w * SS + s;
          else           off = (long)(b * HH + h) * (SS * WW) + (long)s * WW + w;
          out_bf[off] = f2bf(v);
        }
      }
    }
  }
}

// ---------------- MFMA flash attention, 32-query waves + K/V prefetch ----------------
// One wave per (b,h, 32-query tile) [R2 structure, 122 us proven], plus
// 1-tile-deep register double-buffer of K and V fragments so global-load
// latency overlaps the previous tile's MFMA+softmax chain. Loop unrolled x2
// (A/B buffers) to avoid dynamic register indexing. launch_bounds(64,2)
// caps unified regs at 256 (live set ~240, no spill) -> 2 waves/SIMD, and
// the 2048-wave grid is then fully co-resident. In-loop syncs are
// lgkmcnt-only: a __syncthreads would drain vmcnt and kill the prefetch.
#define LOADKV(KF, VF, KB)                                                          \
  {                                                                                 \
    _Pragma("unroll") for (int mt = 0; mt < 4; ++mt)                                \
      _Pragma("unroll") for (int c = 0; c < 2; ++c)                                 \
        KF[mt][c] = *(const s16x8*)(Kp + ((KB) + mt * 16 + l16) * WW + c * 32 + quad * 8); \
    _Pragma("unroll") for (int ni = 0; ni < 4; ++ni)                                \
      _Pragma("unroll") for (int c = 0; c < 2; ++c)                                 \
        VF[ni][c] = *(const s16x8*)(Vp + (ni * 16 + l16) * SS + (KB) + c * 32 + quad * 8); \
  }

#define COMPUTE(KF, VF, KT)                                                         \
  {                                                                                 \
    const int kb_ = (KT)*64;                                                        \
    f32x4 sc[4][2] = {};                                                            \
    _Pragma("unroll") for (int mt = 0; mt < 4; ++mt)                                \
      _Pragma("unroll") for (int nt = 0; nt < 2; ++nt)                              \
        _Pragma("unroll") for (int c = 0; c < 2; ++c)                               \
          sc[mt][nt] = __builtin_amdgcn_mfma_f32_16x16x32_bf16(KF[mt][c], qf[nt][c], sc[mt][nt], 0, 0, 0); \
    if ((KT) == ktiles - 1) {                                                       \
      _Pragma("unroll") for (int mt = 0; mt < 4; ++mt)                              \
        _Pragma("unroll") for (int nt = 0; nt < 2; ++nt)                            \
          _Pragma("unroll") for (int r = 0; r < 4; ++r)                             \
            if (kb_ + mt * 16 + quad * 4 + r > qb + nt * 16 + l16)                  \
              sc[mt][nt][r] = -__builtin_inff();                                    \
    }                                                                               \
    float alpha[2];                                                                 \
    _Pragma("unroll") for (int nt = 0; nt < 2; ++nt) {                              \
      float mx = sc[0][nt][0];                                                      \
      _Pragma("unroll") for (int mt = 0; mt < 4; ++mt)                              \
        _Pragma("unroll") for (int r = 0; r < 4; ++r) mx = fmaxf(mx, sc[mt][nt][r]); \
      mx = fmaxf(mx, __shfl_xor(mx, 16));                                           \
      mx = fmaxf(mx, __shfl_xor(mx, 32));                                           \
      float mn = fmaxf(m[nt], mx);                                                  \
      alpha[nt] = exp2f(m[nt] - mn);                                                \
      float s = 0.f;                                                                \
      _Pragma("unroll") for (int mt = 0; mt < 4; ++mt)                              \
        _Pragma("unroll") for (int r = 0; r < 4; ++r) {                             \
          float p = exp2f(sc[mt][nt][r] - mn);                                      \
          sc[mt][nt][r] = p;                                                        \
          s += p;                                                                   \
        }                                                                           \
      s += __shfl_xor(s, 16);                                                       \
      s += __shfl_xor(s, 32);                                                       \
      l[nt] = l[nt] * alpha[nt] + s;                                                \
      m[nt] = mn;                                                                   \
    }                                                                               \
    _Pragma("unroll") for (int mi = 0; mi < 2; ++mi)                                \
      _Pragma("unroll") for (int r = 0; r < 4; ++r) {                               \
        float aT = __shfl(alpha[mi], quad * 4 + r);                                 \
        _Pragma("unroll") for (int ni = 0; ni < 4; ++ni) O[mi][ni][r] *= aT;        \
      }                                                                             \
    asm volatile("s_waitcnt lgkmcnt(0)" ::: "memory"); /* WAR on Pl */              \
    _Pragma("unroll") for (int mt = 0; mt < 4; ++mt)                                \
      _Pragma("unroll") for (int nt = 0; nt < 2; ++nt) {                            \
        ushort4 pw = make_ushort4(f2bf(sc[mt][nt][0]), f2bf(sc[mt][nt][1]),         \
                                  f2bf(sc[mt][nt][2]), f2bf(sc[mt][nt][3]));        \
        *(ushort4*)(Pl + (nt * 16 + l16) * LDP + mt * 16 + quad * 4) = pw;          \
      }                                                                             \
    asm volatile("s_waitcnt lgkmcnt(0)" ::: "memory"); /* RAW on Pl */              \
    s16x8 pf[2][2];                                                                 \
    _Pragma("unroll") for (int mi = 0; mi < 2; ++mi)                                \
      _Pragma("unroll") for (int c = 0; c < 2; ++c)                                 \
        pf[mi][c] = *(const s16x8*)(Pl + (mi * 16 + l16) * LDP + c * 32 + quad * 8); \
    _Pragma("unroll") for (int mi = 0; mi < 2; ++mi)                                \
      _Pragma("unroll") for (int ni = 0; ni < 4; ++ni)                              \
        _Pragma("unroll") for (int c = 0; c < 2; ++c)                               \
          O[mi][ni] = __builtin_amdgcn_mfma_f32_16x16x32_bf16(pf[mi][c], VF[ni][c], O[mi][ni], 0, 0, 0); \
  }

__global__ __launch_bounds__(64, 2) void k_attn_mfma(const unsigned short* __restrict__ Q,
                                                     const unsigned short* __restrict__ K,
                                                     const unsigned short* __restrict__ Vt,
                                                     unsigned short* __restrict__ hm) {
  constexpr int LDP = 72;  // b128 reads 16B-aligned, 2-way bank alias (free)
  __shared__ __align__(16) unsigned short Pl[32 * LDP];
  const int qb = (int)(gridDim.x - 1 - blockIdx.x) * 32;  // longest blocks first
  const int bh = blockIdx.y;
  const int lane = threadIdx.x;
  const int quad = lane >> 4, l16 = lane & 15;
  const unsigned short* Qp = Q + (size_t)bh * SS * WW;
  const unsigned short* Kp = K + (size_t)bh * SS * WW;
  const unsigned short* Vp = Vt + (size_t)bh * WW * SS;

  // Q B-fragments (loop-invariant): B[n=q_local=l16][k=dim=quad*8+j]
  s16x8 qf[2][2];
#pragma unroll
  for (int nt = 0; nt < 2; ++nt)
#pragma unroll
    for (int c = 0; c < 2; ++c)
      qf[nt][c] = *(const s16x8*)(Qp + (qb + nt * 16 + l16) * WW + c * 32 + quad * 8);

  f32x4 O[2][4] = {};  // C/D: row=q=quad*4+r (+16*mi), col=dim=l16 (+16*ni)
  float m[2], l[2];
  m[0] = m[1] = -__builtin_inff();
  l[0] = l[1] = 0.f;

  const int ktiles = qb / 64 + 1;
  s16x8 kfA[4][2], vfA[4][2], kfB[4][2], vfB[4][2];
  LOADKV(kfA, vfA, 0)
  for (int kt0 = 0; kt0 < ktiles; kt0 += 2) {
    if (kt0 + 1 < ktiles) LOADKV(kfB, vfB, (kt0 + 1) * 64)
    COMPUTE(kfA, vfA, kt0)
    if (kt0 + 1 >= ktiles) break;
    if (kt0 + 2 < ktiles) LOADKV(kfA, vfA, (kt0 + 2) * 64)
    COMPUTE(kfB, vfB, kt0 + 1)
  }

  // epilogue: divide by l (broadcast per C/D row), write head-merged (B,S,D)
  const int b = bh >> 4, h = bh & 15;
#pragma unroll
  for (int mi = 0; mi < 2; ++mi)
#pragma unroll
    for (int r = 0; r < 4; ++r) {
      float linv = 1.f / __shfl(l[mi], quad * 4 + r);
      int q = qb + mi * 16 + quad * 4 + r;
#pragma unroll
      for (int ni = 0; ni < 4; ++ni)
        hm[(size_t)(b * SS + q) * DD + h * WW + ni * 16 + l16] = f2bf(O[mi][ni][r] * linv);
    }
}

extern "C" void kernel_launch(void* const* d_in, const int* in_sizes, int n_in,
                              void* d_out, int out_size, void* d_ws, size_t ws_size,
                              hipStream_t stream) {
  const float* x  = (const float*)d_in[0];
  // d_in[1] = seg : unused by the reference
  const float* Wq = (const float*)d_in[2];
  const float* bq = (const float*)d_in[3];
  const float* Wk = (const float*)d_in[4];
  const float* bk = (const float*)d_in[5];
  const float* Wv = (const float*)d_in[6];
  const float* bv = (const float*)d_in[7];
  const float* Wo = (const float*)d_in[8];
  const float* bo = (const float*)d_in[9];
  float* out = (float*)d_out;

  char* ws = (char*)d_ws;
  unsigned short* xb  = (unsigned short*)(ws);                      // 8 MB
  unsigned short* Wtq = (unsigned short*)(ws + (size_t)( 8 << 20)); // 2 MB each
  unsigned short* Wtk = (unsigned short*)(ws + (size_t)(10 << 20));
  unsigned short* Wtv = (unsigned short*)(ws + (size_t)(12 << 20));
  unsigned short* Wto = (unsigned short*)(ws + (size_t)(14 << 20));
  unsigned short* Qb  = (unsigned short*)(ws + (size_t)(16 << 20)); // 8 MB (B,H,S,W)
  unsigned short* Kb  = (unsigned short*)(ws + (size_t)(24 << 20)); // 8 MB (B,H,S,W)
  unsigned short* Vtb = (unsigned short*)(ws + (size_t)(32 << 20)); // 8 MB (B,H,W,S)
  unsigned short* hm  = (unsigned short*)(ws + (size_t)(40 << 20)); // 8 MB (B,S,D)

  k_convert_x<<<dim3(MM * DD / 1024), 256, 0, stream>>>(x, xb);

  dim3 tg(32, 32), tb(32, 8);
  k_transpose_w<<<tg, tb, 0, stream>>>(Wq, Wtq);
  k_transpose_w<<<tg, tb, 0, stream>>>(Wk, Wtk);
  k_transpose_w<<<tg, tb, 0, stream>>>(Wv, Wtv);
  k_transpose_w<<<tg, tb, 0, stream>>>(Wo, Wto);

  dim3 gg(DD / 64, MM / 64);  // (16, 64)
  // Q pre-scaled by log2(e)/sqrt(64) so softmax runs in exp2 domain
  k_gemm<<<gg, 256, 0, stream>>>(xb, Wtq, bq, Qb, nullptr, 0, 0.125f * 1.4426950408889634f);
  k_gemm<<<gg, 256, 0, stream>>>(xb, Wtk, bk, Kb, nullptr, 2, 1.0f);    // K head-layout
  k_gemm<<<gg, 256, 0, stream>>>(xb, Wtv, bv, Vtb, nullptr, 1, 1.0f);   // V^T per head
  dim3 ag(SS / 32, BB * HH);  // (64, 32) = 2048 single-wave blocks
  k_attn_mfma<<<ag, 64, 0, stream>>>(Qb, Kb, Vtb, hm);

  k_gemm<<<gg, 256, 0, stream>>>(hm, Wto, bo, nullptr, out, 3, 1.0f);   // final projection, fp32
}

// Round 6
// 249.784 us; speedup vs baseline: 1.7114x; 1.2131x over previous
//
#include <hip/hip_runtime.h>

#define BB 2
#define SS 2048
#define DD 1024
#define HH 16
#define WW 64
#define MM (BB*SS)  // 4096

typedef float f32x4 __attribute__((ext_vector_type(4)));
typedef short s16x8 __attribute__((ext_vector_type(8)));

__device__ __forceinline__ unsigned short f2bf(float f) {
  return __builtin_bit_cast(unsigned short, (__bf16)f);
}
__device__ __forceinline__ float bf2f(unsigned short u) {
  return (float)__builtin_bit_cast(__bf16, u);
}
// async global->LDS DMA, 16B per lane; lds dst must be wave-uniform (HW adds lane*16)
__device__ __forceinline__ void dma16(const unsigned short* g, unsigned short* l) {
  __builtin_amdgcn_global_load_lds(
      (const __attribute__((address_space(1))) unsigned int*)g,
      (__attribute__((address_space(3))) unsigned int*)l, 16, 0, 0);
}

// ---------------- pre-pass: x fp32 -> bf16 ----------------
__global__ __launch_bounds__(256) void k_convert_x(const float* __restrict__ x,
                                                   unsigned short* __restrict__ xb) {
  int i = (blockIdx.x * 256 + threadIdx.x) * 4;
  float4 v = *(const float4*)(x + i);
  ushort4 o = make_ushort4(f2bf(v.x), f2bf(v.y), f2bf(v.z), f2bf(v.w));
  *(ushort4*)(xb + i) = o;
}

// ---------------- pre-pass: W (KxN fp32) -> Wt (NxK bf16) ----------------
__global__ __launch_bounds__(256) void k_transpose_w(const float* __restrict__ Wm,
                                                     unsigned short* __restrict__ Wt) {
  __shared__ float tile[32][33];
  int bn = blockIdx.x * 32;
  int bk = blockIdx.y * 32;
  int tx = threadIdx.x;
  int ty = threadIdx.y;
#pragma unroll
  for (int r = 0; r < 4; ++r)
    tile[ty + r * 8][tx] = Wm[(bk + ty + r * 8) * DD + bn + tx];
  __syncthreads();
#pragma unroll
  for (int r = 0; r < 4; ++r)
    Wt[(bn + ty + r * 8) * DD + bk + tx] = f2bf(tile[tx][ty + r * 8]);
}

// ---------------- bf16 MFMA GEMM: C = A(M,K) * Bt(N,K)^T + bias ----------------
// 64x64 tile, BK=32, global_load_lds (width 16) staging with XOR-swizzled LDS.
// modes: 0 = bf16 head-layout scaled (Q); 1 = bf16 per-head transposed (V^T);
//        2 = bf16 head-layout (K); 3 = fp32 row-major (final output)
__global__ __launch_bounds__(256) void k_gemm(const unsigned short* __restrict__ A,
                                              const unsigned short* __restrict__ Bt,
                                              const float* __restrict__ bias,
                                              unsigned short* __restrict__ out_bf,
                                              float* __restrict__ out_f,
                                              int mode, float oscale) {
  __shared__ __align__(16) unsigned short As[64 * 32];  // 4 KB
  __shared__ __align__(16) unsigned short Bs[64 * 32];  // 4 KB
  const int m0 = blockIdx.y * 64, n0 = blockIdx.x * 64;
  const int t = threadIdx.x;
  const int wv = t >> 6, lane = t & 63;
  const int quad = lane >> 4, l16 = lane & 15;
  const int wm = (wv >> 1) * 32, wn = (wv & 1) * 32;
  const int drow = wv * 16 + (lane >> 2);      // tile row this lane fetches
  const int dpb = lane & 3;                    // physical 16B block in row
  const int dcol = ((dpb ^ (drow & 3)) << 3);  // swizzled logical col (elems)
  const unsigned short* Arow = A + (size_t)(m0 + drow) * DD + dcol;
  const unsigned short* Brow = Bt + (size_t)(n0 + drow) * DD + dcol;
  unsigned short* AsDst = As + wv * 512;
  unsigned short* BsDst = Bs + wv * 512;
  f32x4 acc[2][2] = {};

  for (int k0 = 0; k0 < DD; k0 += 32) {
    __syncthreads();
    dma16(Arow + k0, AsDst);
    dma16(Brow + k0, BsDst);
    asm volatile("s_waitcnt vmcnt(0)" ::: "memory");
    __syncthreads();
    s16x8 af[2], bfr[2];
#pragma unroll
    for (int i = 0; i < 2; ++i) {
      int ra = wm + i * 16 + l16;
      int rb = wn + i * 16 + l16;
      af[i]  = *(const s16x8*)(As + ra * 32 + ((quad ^ (ra & 3)) << 3));
      bfr[i] = *(const s16x8*)(Bs + rb * 32 + ((quad ^ (rb & 3)) << 3));
    }
#pragma unroll
    for (int mi = 0; mi < 2; ++mi)
#pragma unroll
      for (int ni = 0; ni < 2; ++ni)
        acc[mi][ni] = __builtin_amdgcn_mfma_f32_16x16x32_bf16(af[mi], bfr[ni], acc[mi][ni], 0, 0, 0);
  }

#pragma unroll
  for (int mi = 0; mi < 2; ++mi) {
#pragma unroll
    for (int ni = 0; ni < 2; ++ni) {
      int col = n0 + wn + ni * 16 + l16;
      float bb = bias[col];
#pragma unroll
      for (int r = 0; r < 4; ++r) {
        int row = m0 + wm + mi * 16 + quad * 4 + r;  // C/D: row = quad*4 + reg
        float v = (acc[mi][ni][r] + bb) * oscale;
        if (mode == 3) {
          out_f[row * DD + col] = v;
        } else {
          int b = row >> 11, s = row & (SS - 1);
          int h = col >> 6, w = col & 63;
          long off;
          if (mode == 1) off = (long)(b * HH + h) * (SS * WW) + (long)w * SS + s;
          else           off = (long)(b * HH + h) * (SS * WW) + (long)s * WW + w;
          out_bf[off] = f2bf(v);
        }
      }
    }
  }
}

// ---------------- MFMA flash attention: LDS-staged, DMA double-buffered ----------------
// Block = 256 threads = 4 waves on a 128-query strip of one (b,h); wave wv owns
// queries [qs+wv*32, qs+wv*32+31]. K/V 64-key tiles are DMA'd (global_load_lds
// x16) into double-buffered LDS, each wave staging 16 rows (4 DMAs/tile); all
// waves consume the shared tile. Pipeline per tile: vmcnt(0) -> barrier ->
// DMA(kt+1) -> compute(kt): next tile's DMA overlaps this tile's MFMA+softmax.
// LDS tiles are XOR-swizzled (phys 16B-block = logical ^ (row&7)) since DMA
// lands at base+lane*16 (no padding possible); fragment ds_reads then hit 8
// distinct blocks per quad -> 2-way bank alias only (free, m136).
// exp2-domain softmax (Q pre-scaled by log2(e)/8); P->LDS roundtrip per-wave.
__global__ __launch_bounds__(256, 2) void k_attn_mfma(const unsigned short* __restrict__ Q,
                                                      const unsigned short* __restrict__ K,
                                                      const unsigned short* __restrict__ Vt,
                                                      unsigned short* __restrict__ hm) {
  constexpr int LDP = 72;
  __shared__ __align__(16) unsigned short Kbuf[2][64 * 64];  // 16 KB
  __shared__ __align__(16) unsigned short Vbuf[2][64 * 64];  // 16 KB
  __shared__ __align__(16) unsigned short Pl4[4][32 * LDP];  // 18.4 KB
  const int strip = (int)(gridDim.x - 1 - blockIdx.x);  // longest blocks first
  const int qs = strip * 128;
  const int bh = blockIdx.y;
  const int t = threadIdx.x;
  const int wv = t >> 6, lane = t & 63;
  const int quad = lane >> 4, l16 = lane & 15;
  const int qb = qs + wv * 32;   // this wave's query base
  const int q_hi = qb + 31;
  unsigned short* Pl = Pl4[wv];
  const unsigned short* Qp = Q + (size_t)bh * SS * WW;
  const unsigned short* Kp = K + (size_t)bh * SS * WW;
  const unsigned short* Vp = Vt + (size_t)bh * WW * SS;

  // staging geometry: lane = 8*rr + cc; DMA d covers rows wv*16 + d*8 .. +7
  const int rr = lane >> 3, cc = lane & 7;
  const int srow = wv * 16 + rr;               // row within 64-row tile (d adds 8)
  const int scol = ((cc ^ (rr & 7)) << 3);     // swizzled logical col (elems)

  // Q B-fragments (loop-invariant): B[n=q_local=l16][k=dim=quad*8+j]
  s16x8 qf[2][2];
#pragma unroll
  for (int nt = 0; nt < 2; ++nt)
#pragma unroll
    for (int c = 0; c < 2; ++c)
      qf[nt][c] = *(const s16x8*)(Qp + (qb + nt * 16 + l16) * WW + c * 32 + quad * 8);

  f32x4 O[2][4] = {};  // C/D: row=q=quad*4+r (+16*mi), col=dim=l16 (+16*ni)
  float m[2], l[2];
  m[0] = m[1] = -__builtin_inff();
  l[0] = l[1] = 0.f;

  const int nkt = qs / 64 + 2;  // tiles needed by wave 3 (qs is a multiple of 128)

  // prologue: stage tile 0 into buffer 0
#pragma unroll
  for (int d = 0; d < 2; ++d) {
    dma16(Kp + (size_t)(srow + d * 8) * WW + scol, &Kbuf[0][(wv * 16 + d * 8) * 64]);
    dma16(Vp + (size_t)(srow + d * 8) * SS + scol, &Vbuf[0][(wv * 16 + d * 8) * 64]);
  }

  for (int kt = 0; kt < nkt; ++kt) {
    const int kb = kt * 64;
    asm volatile("s_waitcnt vmcnt(0)" ::: "memory");  // this tile's DMA landed
    __syncthreads();                                  // all waves' DMA visible; prev compute done
    if (kt + 1 < nkt) {                               // prefetch next tile (overlaps compute)
      const int nb = (kt + 1) & 1;
      const int kbn = kb + 64;
#pragma unroll
      for (int d = 0; d < 2; ++d) {
        dma16(Kp + (size_t)(kbn + srow + d * 8) * WW + scol, &Kbuf[nb][(wv * 16 + d * 8) * 64]);
        dma16(Vp + (size_t)(srow + d * 8) * SS + kbn + scol, &Vbuf[nb][(wv * 16 + d * 8) * 64]);
      }
    }
    if (kb > q_hi) continue;  // wave-uniform: this wave's causal range done (still hits barriers)
    const unsigned short* Kb_ = Kbuf[kt & 1];
    const unsigned short* Vb_ = Vbuf[kt & 1];

    // K A-fragments from LDS: row=key_local, logical block c*4+quad, phys = lb^(row&7)
    s16x8 kf[4][2];
#pragma unroll
    for (int mt = 0; mt < 4; ++mt)
#pragma unroll
      for (int c = 0; c < 2; ++c)
        kf[mt][c] = *(const s16x8*)(Kb_ + (mt * 16 + l16) * 64 + (((c * 4 + quad) ^ (l16 & 7)) << 3));

    // S^T tiles: row=key_local=quad*4+r (+16*mt), col=q_local=l16 (+16*nt)
    f32x4 sc[4][2] = {};
#pragma unroll
    for (int mt = 0; mt < 4; ++mt)
#pragma unroll
      for (int nt = 0; nt < 2; ++nt)
#pragma unroll
        for (int c = 0; c < 2; ++c)
          sc[mt][nt] = __builtin_amdgcn_mfma_f32_16x16x32_bf16(kf[mt][c], qf[nt][c], sc[mt][nt], 0, 0, 0);

    if (kb + 63 > qb) {  // diagonal-overlapping tile: causal mask
#pragma unroll
      for (int mt = 0; mt < 4; ++mt)
#pragma unroll
        for (int nt = 0; nt < 2; ++nt)
#pragma unroll
          for (int r = 0; r < 4; ++r)
            if (kb + mt * 16 + quad * 4 + r > qb + nt * 16 + l16)
              sc[mt][nt][r] = -__builtin_inff();
    }

    // online softmax (exp2 domain); stats per q = nt*16 + l16
    float alpha[2];
#pragma unroll
    for (int nt = 0; nt < 2; ++nt) {
      float mx = sc[0][nt][0];
#pragma unroll
      for (int mt = 0; mt < 4; ++mt)
#pragma unroll
        for (int r = 0; r < 4; ++r) mx = fmaxf(mx, sc[mt][nt][r]);
      mx = fmaxf(mx, __shfl_xor(mx, 16));
      mx = fmaxf(mx, __shfl_xor(mx, 32));
      float mn = fmaxf(m[nt], mx);
      alpha[nt] = __builtin_amdgcn_exp2f(m[nt] - mn);
      float s = 0.f;
#pragma unroll
      for (int mt = 0; mt < 4; ++mt)
#pragma unroll
        for (int r = 0; r < 4; ++r) {
          float p = __builtin_amdgcn_exp2f(sc[mt][nt][r] - mn);
          sc[mt][nt][r] = p;
          s += p;
        }
      s += __shfl_xor(s, 16);
      s += __shfl_xor(s, 32);
      l[nt] = l[nt] * alpha[nt] + s;
      m[nt] = mn;
    }

    // rescale O: rows q = mi*16 + quad*4 + r -> alpha from lane (quad*4+r)
#pragma unroll
    for (int mi = 0; mi < 2; ++mi)
#pragma unroll
      for (int r = 0; r < 4; ++r) {
        float aT = __shfl(alpha[mi], quad * 4 + r);
#pragma unroll
        for (int ni = 0; ni < 4; ++ni) O[mi][ni][r] *= aT;
      }

    // P -> per-wave LDS region (layout transform C/D -> A-operand)
    asm volatile("s_waitcnt lgkmcnt(0)" ::: "memory");  // WAR: prev pf reads done
#pragma unroll
    for (int mt = 0; mt < 4; ++mt)
#pragma unroll
      for (int nt = 0; nt < 2; ++nt) {
        ushort4 pw = make_ushort4(f2bf(sc[mt][nt][0]), f2bf(sc[mt][nt][1]),
                                  f2bf(sc[mt][nt][2]), f2bf(sc[mt][nt][3]));
        *(ushort4*)(Pl + (nt * 16 + l16) * LDP + mt * 16 + quad * 4) = pw;
      }
    asm volatile("s_waitcnt lgkmcnt(0)" ::: "memory");  // RAW: stores visible

    // V^T B-fragments from LDS (kf dead by now -> low peak VGPR)
    s16x8 vf[4][2];
#pragma unroll
    for (int ni = 0; ni < 4; ++ni)
#pragma unroll
      for (int c = 0; c < 2; ++c)
        vf[ni][c] = *(const s16x8*)(Vb_ + (ni * 16 + l16) * 64 + (((c * 4 + quad) ^ (l16 & 7)) << 3));

    // P A-fragments
    s16x8 pf[2][2];
#pragma unroll
    for (int mi = 0; mi < 2; ++mi)
#pragma unroll
      for (int c = 0; c < 2; ++c)
        pf[mi][c] = *(const s16x8*)(Pl + (mi * 16 + l16) * LDP + c * 32 + quad * 8);

    // O += P * V^T
#pragma unroll
    for (int mi = 0; mi < 2; ++mi)
#pragma unroll
      for (int ni = 0; ni < 4; ++ni)
#pragma unroll
        for (int c = 0; c < 2; ++c)
          O[mi][ni] = __builtin_amdgcn_mfma_f32_16x16x32_bf16(pf[mi][c], vf[ni][c], O[mi][ni], 0, 0, 0);
  }

  // epilogue: divide by l (broadcast per C/D row), write head-merged (B,S,D)
  const int b = bh >> 4, h = bh & 15;
#pragma unroll
  for (int mi = 0; mi < 2; ++mi)
#pragma unroll
    for (int r = 0; r < 4; ++r) {
      float linv = 1.f / __shfl(l[mi], quad * 4 + r);
      int q = qb + mi * 16 + quad * 4 + r;
#pragma unroll
      for (int ni = 0; ni < 4; ++ni)
        hm[(size_t)(b * SS + q) * DD + h * WW + ni * 16 + l16] = f2bf(O[mi][ni][r] * linv);
    }
}

extern "C" void kernel_launch(void* const* d_in, const int* in_sizes, int n_in,
                              void* d_out, int out_size, void* d_ws, size_t ws_size,
                              hipStream_t stream) {
  const float* x  = (const float*)d_in[0];
  // d_in[1] = seg : unused by the reference
  const float* Wq = (const float*)d_in[2];
  const float* bq = (const float*)d_in[3];
  const float* Wk = (const float*)d_in[4];
  const float* bk = (const float*)d_in[5];
  const float* Wv = (const float*)d_in[6];
  const float* bv = (const float*)d_in[7];
  const float* Wo = (const float*)d_in[8];
  const float* bo = (const float*)d_in[9];
  float* out = (float*)d_out;

  char* ws = (char*)d_ws;
  unsigned short* xb  = (unsigned short*)(ws);                      // 8 MB
  unsigned short* Wtq = (unsigned short*)(ws + (size_t)( 8 << 20)); // 2 MB each
  unsigned short* Wtk = (unsigned short*)(ws + (size_t)(10 << 20));
  unsigned short* Wtv = (unsigned short*)(ws + (size_t)(12 << 20));
  unsigned short* Wto = (unsigned short*)(ws + (size_t)(14 << 20));
  unsigned short* Qb  = (unsigned short*)(ws + (size_t)(16 << 20)); // 8 MB (B,H,S,W)
  unsigned short* Kb  = (unsigned short*)(ws + (size_t)(24 << 20)); // 8 MB (B,H,S,W)
  unsigned short* Vtb = (unsigned short*)(ws + (size_t)(32 << 20)); // 8 MB (B,H,W,S)
  unsigned short* hm  = (unsigned short*)(ws + (size_t)(40 << 20)); // 8 MB (B,S,D)

  k_convert_x<<<dim3(MM * DD / 1024), 256, 0, stream>>>(x, xb);

  dim3 tg(32, 32), tb(32, 8);
  k_transpose_w<<<tg, tb, 0, stream>>>(Wq, Wtq);
  k_transpose_w<<<tg, tb, 0, stream>>>(Wk, Wtk);
  k_transpose_w<<<tg, tb, 0, stream>>>(Wv, Wtv);
  k_transpose_w<<<tg, tb, 0, stream>>>(Wo, Wto);

  dim3 gg(DD / 64, MM / 64);  // (16, 64)
  // Q pre-scaled by log2(e)/sqrt(64) so softmax runs in exp2 domain
  k_gemm<<<gg, 256, 0, stream>>>(xb, Wtq, bq, Qb, nullptr, 0, 0.125f * 1.4426950408889634f);
  k_gemm<<<gg, 256, 0, stream>>>(xb, Wtk, bk, Kb, nullptr, 2, 1.0f);    // K head-layout
  k_gemm<<<gg, 256, 0, stream>>>(xb, Wtv, bv, Vtb, nullptr, 1, 1.0f);   // V^T per head
  dim3 ag(SS / 128, BB * HH);  // (16, 32) = 512 four-wave blocks
  k_attn_mfma<<<ag, 256, 0, stream>>>(Qb, Kb, Vtb, hm);

  k_gemm<<<gg, 256, 0, stream>>>(hm, Wto, bo, nullptr, out, 3, 1.0f);   // final projection, fp32
}